// Round 17
// baseline (205.873 us; speedup 1.0000x reference)
//
#include <hip/hip_runtime.h>

#define IN_DIM 256
#define HID 64
#define HEADS 4
#define C1 256   // HID*HEADS

typedef __attribute__((ext_vector_type(4))) float  f32x4;
typedef __attribute__((ext_vector_type(2))) float  f32x2;
typedef __attribute__((ext_vector_type(8))) short  short8;
typedef __attribute__((ext_vector_type(8))) unsigned short ushort8;
typedef __attribute__((ext_vector_type(4))) unsigned short ushort4v;

static __device__ __forceinline__ unsigned short f2bf(float f) {
  union { float f; unsigned int u; } v; v.f = f;
  unsigned int r = v.u + 0x7fffu + ((v.u >> 16) & 1u);   // RNE
  return (unsigned short)(r >> 16);
}
static __device__ __forceinline__ float bf2f(unsigned short u) {
  union { unsigned int u; float f; } v; v.u = ((unsigned int)u) << 16;
  return v.f;
}
static __device__ __forceinline__ unsigned char f2fp8(float f) {
  unsigned int p = __builtin_amdgcn_cvt_pk_fp8_f32(f, f, 0u, false);
  return (unsigned char)(p & 0xFFu);
}

// ---------------------------------------------------------------------------
// prep: weight transposes (f32 -> bf16, [k][n] -> [n][k]) + zero counts/done
// ---------------------------------------------------------------------------

__global__ __launch_bounds__(256) void prep_kernel(const float* __restrict__ W1,
                                                   unsigned short* __restrict__ W1t,
                                                   const float* __restrict__ W2,
                                                   unsigned short* __restrict__ W2t,
                                                   int* __restrict__ counts,
                                                   int* __restrict__ done, int N) {
  int t = blockIdx.x * 256 + threadIdx.x;
  if (t == 0) *done = 0;
  if (t < 256 * 256) {
    int k = t & 255, n = t >> 8;
    W1t[n * 256 + k] = f2bf(W1[k * 256 + n]);
  } else if (t < 256 * 256 + 64 * 256) {
    int u = t - 256 * 256;
    int k = u & 255, n = u >> 8;
    W2t[n * 256 + k] = f2bf(W2[k * 64 + n]);
  } else {
    int i = t - (256 * 256 + 64 * 256);
    if (i < N) counts[i] = 0;
  }
}

// ---------------------------------------------------------------------------
// CSR build — rank trick
// ---------------------------------------------------------------------------

__global__ __launch_bounds__(256) void hist_kernel(const int* __restrict__ ei,
                                                   int E, int N,
                                                   int* __restrict__ counts,
                                                   int* __restrict__ rank) {
  int e = blockIdx.x * 256 + threadIdx.x;
  if (e >= E + N) return;
  int dst = (e < E) ? ei[(size_t)E + e] : (e - E);
  rank[e] = atomicAdd(&counts[dst], 1);
}

__global__ __launch_bounds__(256) void scan12_kernel(const int* __restrict__ counts,
                                                     int* __restrict__ blocksums,
                                                     int* __restrict__ blockoff,
                                                     int* __restrict__ done,
                                                     int N, int NB) {
  int tid = threadIdx.x;
  int base = blockIdx.x * 1024 + tid * 4;
  int s = 0;
  if (base + 3 < N) {
    int4 v = *(const int4*)&counts[base];
    s = v.x + v.y + v.z + v.w;
  } else {
    for (int i = 0; i < 4; ++i) if (base + i < N) s += counts[base + i];
  }
  __shared__ int red[256];
  red[tid] = s;
  __syncthreads();
  for (int off = 128; off; off >>= 1) {
    if (tid < off) red[tid] += red[tid + off];
    __syncthreads();
  }
  __shared__ int amLast;
  if (tid == 0) {
    blocksums[blockIdx.x] = red[0];
    __threadfence();
    amLast = (atomicAdd(done, 1) == NB - 1);
  }
  __syncthreads();
  if (amLast && tid < 64) {
    __threadfence();
    int lane = tid;
    int carry = 0;
    for (int b = 0; b < NB; b += 64) {
      int v = (b + lane < NB) ? blocksums[b + lane] : 0;
      int incl = v;
      #pragma unroll
      for (int off = 1; off < 64; off <<= 1) {
        int t = __shfl_up(incl, off);
        if (lane >= off) incl += t;
      }
      if (b + lane < NB) blockoff[b + lane] = carry + incl - v;
      carry += __shfl(incl, 63);
    }
    if (lane == 0) blockoff[NB] = carry;
  }
}

__global__ __launch_bounds__(256) void scan3_kernel(const int* __restrict__ counts,
                                                    const int* __restrict__ blockoff,
                                                    int* __restrict__ indptr, int N, int NB) {
  int tid = threadIdx.x;
  int base = blockIdx.x * 1024 + tid * 4;
  int c0 = 0, c1 = 0, c2 = 0, c3 = 0;
  if (base + 3 < N) {
    int4 v = *(const int4*)&counts[base];
    c0 = v.x; c1 = v.y; c2 = v.z; c3 = v.w;
  } else {
    if (base + 0 < N) c0 = counts[base + 0];
    if (base + 1 < N) c1 = counts[base + 1];
    if (base + 2 < N) c2 = counts[base + 2];
    if (base + 3 < N) c3 = counts[base + 3];
  }
  int s = c0 + c1 + c2 + c3;
  __shared__ int sc[256];
  sc[tid] = s;
  __syncthreads();
  for (int off = 1; off < 256; off <<= 1) {
    int t = (tid >= off) ? sc[tid - off] : 0;
    __syncthreads();
    sc[tid] += t;
    __syncthreads();
  }
  int p = sc[tid] - s + blockoff[blockIdx.x];
  if (base + 0 < N) { indptr[base + 0] = p; p += c0; }
  if (base + 1 < N) { indptr[base + 1] = p; p += c1; }
  if (base + 2 < N) { indptr[base + 2] = p; p += c2; }
  if (base + 3 < N) { indptr[base + 3] = p; p += c3; }
  if (blockIdx.x == 0 && tid == 0) indptr[N] = blockoff[NB];
}

// fill (atomic-free via rank) fused with layer-1 edge weights.
__global__ __launch_bounds__(256) void fillw_kernel(const int* __restrict__ ei, int E, int N,
                                                    const int* __restrict__ indptr,
                                                    const int* __restrict__ rank,
                                                    int* __restrict__ srcs,
                                                    const float* __restrict__ asrc,
                                                    const float* __restrict__ adst,
                                                    float* __restrict__ w) {
  int e = blockIdx.x * 256 + threadIdx.x;
  if (e >= E + N) return;
  int src, dst;
  if (e < E) { src = ei[e]; dst = ei[(size_t)E + e]; }
  else       { src = e - E; dst = e - E; }
  int pos = indptr[dst] + rank[e];
  srcs[pos] = src;
  float4 as = *(const float4*)&asrc[src * 4];
  float4 ad = *(const float4*)&adst[dst * 4];
  float e0 = as.x + ad.x; e0 = (e0 > 0.f) ? e0 : 0.2f * e0;
  float e1 = as.y + ad.y; e1 = (e1 > 0.f) ? e1 : 0.2f * e1;
  float e2 = as.z + ad.z; e2 = (e2 > 0.f) ? e2 : 0.2f * e2;
  float e3 = as.w + ad.w; e3 = (e3 > 0.f) ? e3 : 0.2f * e3;
  *(float4*)&w[pos * 4] = make_float4(__expf(e0), __expf(e1), __expf(e2), __expf(e3));
}

// ---------------------------------------------------------------------------
// gemm1 fused: H1f8[M,256](fp8 e4m3) = x[M,256](f32) @ W1t^T, alpha1 epilogue.
// BM=128, BN=256, BK=32; 512 threads; LDT3=56; LDS 43KB -> 3 blocks/CU.
// ---------------------------------------------------------------------------

#define LDT2 72   // gemm2 pad
#define LDT3 56   // gemm1 pad (BK=32)

__global__ __launch_bounds__(512) void gemm1_fused(const float* __restrict__ A,
                                                   const unsigned short* __restrict__ Bt,
                                                   unsigned char* __restrict__ C,
                                                   const float* __restrict__ a_src,
                                                   const float* __restrict__ a_dst,
                                                   float* __restrict__ asrc,
                                                   float* __restrict__ adst, int M) {
  const int K = 256;
  __shared__ unsigned short As[128 * LDT3];
  __shared__ unsigned short Bs[256 * LDT3];
  int bm = blockIdx.x * 128;
  int tid = threadIdx.x;
  int wid = tid >> 6, lane = tid & 63;
  int wr = (wid >> 1) * 32, wc = (wid & 1) * 128;
  int l15 = lane & 15, lq = lane >> 4;

  f32x4 acc[2][8];
  #pragma unroll
  for (int i = 0; i < 2; ++i)
    #pragma unroll
    for (int f = 0; f < 8; ++f) acc[i][f] = (f32x4){0,0,0,0};

  for (int k0 = 0; k0 < K; k0 += 32) {
    {
      int r = tid >> 2, c = (tid & 3) * 8;
      int row = bm + r;
      float4 v0 = make_float4(0.f,0.f,0.f,0.f), v1 = v0;
      if (row < M) {
        v0 = *(const float4*)&A[(size_t)row * K + k0 + c];
        v1 = *(const float4*)&A[(size_t)row * K + k0 + c + 4];
      }
      ushort8 o;
      o[0]=f2bf(v0.x); o[1]=f2bf(v0.y); o[2]=f2bf(v0.z); o[3]=f2bf(v0.w);
      o[4]=f2bf(v1.x); o[5]=f2bf(v1.y); o[6]=f2bf(v1.z); o[7]=f2bf(v1.w);
      *(ushort8*)&As[r * LDT3 + c] = o;
    }
    {
      int r = tid >> 1, seg = (tid & 1) * 16;
      ushort8 v0 = *(const ushort8*)&Bt[(size_t)r * K + k0 + seg];
      ushort8 v1 = *(const ushort8*)&Bt[(size_t)r * K + k0 + seg + 8];
      *(ushort8*)&Bs[r * LDT3 + seg]     = v0;
      *(ushort8*)&Bs[r * LDT3 + seg + 8] = v1;
    }
    __syncthreads();

    short8 a0 = *(const short8*)&As[(wr + l15) * LDT3 + lq * 8];
    short8 a1 = *(const short8*)&As[(wr + 16 + l15) * LDT3 + lq * 8];
    #pragma unroll
    for (int f = 0; f < 8; ++f) {
      short8 b = *(const short8*)&Bs[(wc + f * 16 + l15) * LDT3 + lq * 8];
      acc[0][f] = __builtin_amdgcn_mfma_f32_16x16x32_bf16(a0, b, acc[0][f], 0, 0, 0);
      acc[1][f] = __builtin_amdgcn_mfma_f32_16x16x32_bf16(a1, b, acc[1][f], 0, 0, 0);
    }
    __syncthreads();
  }

  #pragma unroll
  for (int r = 0; r < 4; ++r) {
    int row0 = bm + wr + lq * 4 + r;
    int row1 = row0 + 16;
    #pragma unroll
    for (int f = 0; f < 8; ++f) {
      int col = wc + f * 16 + l15;
      if (row0 < M) C[(size_t)row0 * 256 + col] = f2fp8(acc[0][f][r]);
      if (row1 < M) C[(size_t)row1 * 256 + col] = f2fp8(acc[1][f][r]);
    }
  }

  float ps[2][4][2], pd[2][4][2];
  #pragma unroll
  for (int i = 0; i < 2; ++i)
    #pragma unroll
    for (int r = 0; r < 4; ++r) { ps[i][r][0]=0.f; ps[i][r][1]=0.f; pd[i][r][0]=0.f; pd[i][r][1]=0.f; }
  #pragma unroll
  for (int f = 0; f < 8; ++f) {
    int col = wc + f * 16 + l15;
    float av = a_src[col], dv = a_dst[col];
    int hh = f >> 2;
    #pragma unroll
    for (int i = 0; i < 2; ++i)
      #pragma unroll
      for (int r = 0; r < 4; ++r) {
        ps[i][r][hh] += acc[i][f][r] * av;
        pd[i][r][hh] += acc[i][f][r] * dv;
      }
  }
  #pragma unroll
  for (int off = 1; off < 16; off <<= 1) {
    #pragma unroll
    for (int i = 0; i < 2; ++i)
      #pragma unroll
      for (int r = 0; r < 4; ++r) {
        ps[i][r][0] += __shfl_xor(ps[i][r][0], off);
        ps[i][r][1] += __shfl_xor(ps[i][r][1], off);
        pd[i][r][0] += __shfl_xor(pd[i][r][0], off);
        pd[i][r][1] += __shfl_xor(pd[i][r][1], off);
      }
  }
  if (l15 == 0) {
    int hb = wc >> 6;
    #pragma unroll
    for (int i = 0; i < 2; ++i)
      #pragma unroll
      for (int r = 0; r < 4; ++r) {
        int row = bm + wr + lq * 4 + r + i * 16;
        if (row < M) {
          asrc[row * 4 + hb]     = ps[i][r][0];
          asrc[row * 4 + hb + 1] = ps[i][r][1];
          adst[row * 4 + hb]     = pd[i][r][0];
          adst[row * 4 + hb + 1] = pd[i][r][1];
        }
      }
  }
}

// ---------------------------------------------------------------------------
// gemm2 fused: H2b[M,64](bf16) = X2b[M,256](bf16) @ W2t^T, alpha2 in epilogue.
// ---------------------------------------------------------------------------

__global__ __launch_bounds__(256) void gemm2_fused(const unsigned short* __restrict__ A,
                                                   const unsigned short* __restrict__ Bt,
                                                   unsigned short* __restrict__ C,
                                                   const float* __restrict__ a_src,
                                                   const float* __restrict__ a_dst,
                                                   float* __restrict__ asrc,
                                                   float* __restrict__ adst, int M) {
  const int K = 256;
  __shared__ unsigned short As[64 * LDT2];
  __shared__ unsigned short Bs[64 * LDT2];
  __shared__ float sred[64], dred[64];
  int bm = blockIdx.x * 64;
  int tid = threadIdx.x;
  int wid = tid >> 6, lane = tid & 63;
  int wr = (wid >> 1) * 32, wc = (wid & 1) * 32;
  int l15 = lane & 15, lq = lane >> 4;

  f32x4 acc[2][2];
  #pragma unroll
  for (int i = 0; i < 2; ++i) { acc[i][0] = (f32x4){0,0,0,0}; acc[i][1] = (f32x4){0,0,0,0}; }

  for (int k0 = 0; k0 < K; k0 += 64) {
    {
      int r = tid >> 2, seg = (tid & 3) * 16;
      int row = bm + r;
      ushort8 v0 = {0,0,0,0,0,0,0,0}, v1 = {0,0,0,0,0,0,0,0};
      if (row < M) {
        v0 = *(const ushort8*)&A[(size_t)row * K + k0 + seg];
        v1 = *(const ushort8*)&A[(size_t)row * K + k0 + seg + 8];
      }
      *(ushort8*)&As[r * LDT2 + seg]     = v0;
      *(ushort8*)&As[r * LDT2 + seg + 8] = v1;
    }
    {
      int r = tid >> 2, seg = (tid & 3) * 16;
      ushort8 v0 = *(const ushort8*)&Bt[(size_t)r * K + k0 + seg];
      ushort8 v1 = *(const ushort8*)&Bt[(size_t)r * K + k0 + seg + 8];
      *(ushort8*)&Bs[r * LDT2 + seg]     = v0;
      *(ushort8*)&Bs[r * LDT2 + seg + 8] = v1;
    }
    __syncthreads();

    #pragma unroll
    for (int ks = 0; ks < 2; ++ks) {
      short8 a0 = *(const short8*)&As[(wr + l15) * LDT2 + ks * 32 + lq * 8];
      short8 a1 = *(const short8*)&As[(wr + 16 + l15) * LDT2 + ks * 32 + lq * 8];
      #pragma unroll
      for (int f = 0; f < 2; ++f) {
        short8 b = *(const short8*)&Bs[(wc + f * 16 + l15) * LDT2 + ks * 32 + lq * 8];
        acc[0][f] = __builtin_amdgcn_mfma_f32_16x16x32_bf16(a0, b, acc[0][f], 0, 0, 0);
        acc[1][f] = __builtin_amdgcn_mfma_f32_16x16x32_bf16(a1, b, acc[1][f], 0, 0, 0);
      }
    }
    __syncthreads();
  }

  #pragma unroll
  for (int r = 0; r < 4; ++r) {
    int row0 = bm + wr + lq * 4 + r;
    int row1 = row0 + 16;
    #pragma unroll
    for (int f = 0; f < 2; ++f) {
      int col = wc + f * 16 + l15;
      if (row0 < M) C[(size_t)row0 * 64 + col] = f2bf(acc[0][f][r]);
      if (row1 < M) C[(size_t)row1 * 64 + col] = f2bf(acc[1][f][r]);
    }
  }

  float ps[2][4], pd[2][4];
  #pragma unroll
  for (int i = 0; i < 2; ++i)
    #pragma unroll
    for (int r = 0; r < 4; ++r) { ps[i][r] = 0.f; pd[i][r] = 0.f; }
  #pragma unroll
  for (int f = 0; f < 2; ++f) {
    int col = wc + f * 16 + l15;
    float av = a_src[col], dv = a_dst[col];
    #pragma unroll
    for (int i = 0; i < 2; ++i)
      #pragma unroll
      for (int r = 0; r < 4; ++r) {
        ps[i][r] += acc[i][f][r] * av;
        pd[i][r] += acc[i][f][r] * dv;
      }
  }
  #pragma unroll
  for (int off = 1; off < 16; off <<= 1) {
    #pragma unroll
    for (int i = 0; i < 2; ++i)
      #pragma unroll
      for (int r = 0; r < 4; ++r) {
        ps[i][r] += __shfl_xor(ps[i][r], off);
        pd[i][r] += __shfl_xor(pd[i][r], off);
      }
  }
  if ((wid & 1) == 0 && l15 == 0) {
    #pragma unroll
    for (int i = 0; i < 2; ++i)
      #pragma unroll
      for (int r = 0; r < 4; ++r) {
        int rl = wr + lq * 4 + r + i * 16;
        sred[rl] = ps[i][r];
        dred[rl] = pd[i][r];
      }
  }
  __syncthreads();
  if ((wid & 1) == 1 && l15 == 0) {
    #pragma unroll
    for (int i = 0; i < 2; ++i)
      #pragma unroll
      for (int r = 0; r < 4; ++r) {
        int rl = wr + lq * 4 + r + i * 16;
        int row = bm + rl;
        if (row < M) {
          asrc[row] = sred[rl] + ps[i][r];
          adst[row] = dred[rl] + pd[i][r];
        }
      }
  }
}

// ---------------------------------------------------------------------------
// GAT agg layer 1 (fp8 H1): QUARTER-wave per edge (4 slots), 16B/lane uint4,
// 2x unroll -> one VMEM instr covers 4 edges (halved request count).
// lane = (slot = l>>4, j = l&15); feats 16j..16j+15; head h = j>>2.
// ---------------------------------------------------------------------------

__global__ __launch_bounds__(256) void gat1_agg(const unsigned char* __restrict__ H1f8,
                                                const float* __restrict__ w,
                                                const int* __restrict__ indptr,
                                                const int* __restrict__ srcs,
                                                const float* __restrict__ b1,
                                                const float* __restrict__ g1,
                                                const float* __restrict__ be1,
                                                const float* __restrict__ mu1,
                                                const float* __restrict__ var1,
                                                unsigned short* __restrict__ X2b, int N) {
  int n = blockIdx.x * 4 + (threadIdx.x >> 6);
  if (n >= N) return;
  int lane = threadIdx.x & 63;
  int slot = lane >> 4;       // 0..3 edge slot
  int j = lane & 15;          // feat group: feats 16j..16j+15
  int h = j >> 2;             // head
  int start = indptr[n], end = indptr[n + 1];

  f32x2 acc2[8];
  #pragma unroll
  for (int i = 0; i < 8; ++i) acc2[i] = (f32x2){0.f, 0.f};
  float wsum = 0.f;
  int k = start + slot;
  // 2 edges per slot in flight (8 per wave)
  for (; k + 4 < end; k += 8) {
    int s0 = srcs[k], s1 = srcs[k + 4];
    float w0 = w[k * 4 + h], w1v = w[(k + 4) * 4 + h];
    uint4 u0 = *(const uint4*)&H1f8[(size_t)s0 * C1 + j * 16];
    uint4 u1 = *(const uint4*)&H1f8[(size_t)s1 * C1 + j * 16];
    wsum += w0 + w1v;
    {
      f32x2 wv = (f32x2){w0, w0};
      acc2[0] += wv * __builtin_amdgcn_cvt_pk_f32_fp8(u0.x, false);
      acc2[1] += wv * __builtin_amdgcn_cvt_pk_f32_fp8(u0.x, true);
      acc2[2] += wv * __builtin_amdgcn_cvt_pk_f32_fp8(u0.y, false);
      acc2[3] += wv * __builtin_amdgcn_cvt_pk_f32_fp8(u0.y, true);
      acc2[4] += wv * __builtin_amdgcn_cvt_pk_f32_fp8(u0.z, false);
      acc2[5] += wv * __builtin_amdgcn_cvt_pk_f32_fp8(u0.z, true);
      acc2[6] += wv * __builtin_amdgcn_cvt_pk_f32_fp8(u0.w, false);
      acc2[7] += wv * __builtin_amdgcn_cvt_pk_f32_fp8(u0.w, true);
    }
    {
      f32x2 wv = (f32x2){w1v, w1v};
      acc2[0] += wv * __builtin_amdgcn_cvt_pk_f32_fp8(u1.x, false);
      acc2[1] += wv * __builtin_amdgcn_cvt_pk_f32_fp8(u1.x, true);
      acc2[2] += wv * __builtin_amdgcn_cvt_pk_f32_fp8(u1.y, false);
      acc2[3] += wv * __builtin_amdgcn_cvt_pk_f32_fp8(u1.y, true);
      acc2[4] += wv * __builtin_amdgcn_cvt_pk_f32_fp8(u1.z, false);
      acc2[5] += wv * __builtin_amdgcn_cvt_pk_f32_fp8(u1.z, true);
      acc2[6] += wv * __builtin_amdgcn_cvt_pk_f32_fp8(u1.w, false);
      acc2[7] += wv * __builtin_amdgcn_cvt_pk_f32_fp8(u1.w, true);
    }
  }
  for (; k < end; k += 4) {
    int s0 = srcs[k];
    float w0 = w[k * 4 + h];
    uint4 u0 = *(const uint4*)&H1f8[(size_t)s0 * C1 + j * 16];
    wsum += w0;
    f32x2 wv = (f32x2){w0, w0};
    acc2[0] += wv * __builtin_amdgcn_cvt_pk_f32_fp8(u0.x, false);
    acc2[1] += wv * __builtin_amdgcn_cvt_pk_f32_fp8(u0.x, true);
    acc2[2] += wv * __builtin_amdgcn_cvt_pk_f32_fp8(u0.y, false);
    acc2[3] += wv * __builtin_amdgcn_cvt_pk_f32_fp8(u0.y, true);
    acc2[4] += wv * __builtin_amdgcn_cvt_pk_f32_fp8(u0.z, false);
    acc2[5] += wv * __builtin_amdgcn_cvt_pk_f32_fp8(u0.z, true);
    acc2[6] += wv * __builtin_amdgcn_cvt_pk_f32_fp8(u0.w, false);
    acc2[7] += wv * __builtin_amdgcn_cvt_pk_f32_fp8(u0.w, true);
  }
  float acc[16];
  #pragma unroll
  for (int i = 0; i < 8; ++i) { acc[2*i] = acc2[i][0]; acc[2*i+1] = acc2[i][1]; }
  #pragma unroll
  for (int i = 0; i < 16; ++i) {
    acc[i] += __shfl_xor(acc[i], 16);
    acc[i] += __shfl_xor(acc[i], 32);
  }
  wsum += __shfl_xor(wsum, 16);
  wsum += __shfl_xor(wsum, 32);

  if (slot == 0) {
    float inv = 1.f / (wsum + 1e-16f);
    int f = j * 16;
    ushort8 o0, o1;
    #pragma unroll
    for (int i = 0; i < 16; ++i) {
      float val = (acc[i] * inv + b1[f + i] - mu1[f + i]) *
                  (g1[f + i] * rsqrtf(var1[f + i] + 1e-5f)) + be1[f + i];
      val = (val > 0.f) ? val : (__expf(val) - 1.f);
      if (i < 8) o0[i] = f2bf(val); else o1[i - 8] = f2bf(val);
    }
    *(ushort8*)&X2b[(size_t)n * C1 + f]     = o0;
    *(ushort8*)&X2b[(size_t)n * C1 + f + 8] = o1;
  }
}

// ---------------------------------------------------------------------------
// GAT agg layer 2 (fused edge weights, 8-slot geometry): wave per node,
// 8 edge slots, 16B/lane, 2x unroll; w computed inline from asrc2 (L2-hot).
// ---------------------------------------------------------------------------

__global__ __launch_bounds__(256) void gat2_agg(const unsigned short* __restrict__ H2b,
                                                const float* __restrict__ asrc,
                                                const float* __restrict__ adst,
                                                const int* __restrict__ indptr,
                                                const int* __restrict__ srcs,
                                                const float* __restrict__ b2,
                                                const float* __restrict__ g2,
                                                const float* __restrict__ be2,
                                                const float* __restrict__ mu2,
                                                const float* __restrict__ var2,
                                                float* __restrict__ out, int N) {
  int n = blockIdx.x * 4 + (threadIdx.x >> 6);
  if (n >= N) return;
  int lane = threadIdx.x & 63;
  int q = lane >> 3;
  int j = lane & 7;
  int start = indptr[n], end = indptr[n + 1];
  float ad = adst[n];

  float acc[8];
  #pragma unroll
  for (int i = 0; i < 8; ++i) acc[i] = 0.f;
  float wsum = 0.f;

  int k = start + q;
  for (; k + 8 < end; k += 16) {
    int s0 = srcs[k], s1 = srcs[k + 8];
    float e0 = asrc[s0] + ad; e0 = (e0 > 0.f) ? e0 : 0.2f * e0;
    float e1 = asrc[s1] + ad; e1 = (e1 > 0.f) ? e1 : 0.2f * e1;
    float w0 = __expf(e0), w1v = __expf(e1);
    ushort8 r0 = *(const ushort8*)&H2b[(size_t)s0 * HID + j * 8];
    ushort8 r1 = *(const ushort8*)&H2b[(size_t)s1 * HID + j * 8];
    wsum += w0 + w1v;
    #pragma unroll
    for (int i = 0; i < 8; ++i)
      acc[i] += w0 * bf2f(r0[i]) + w1v * bf2f(r1[i]);
  }
  if (k < end) {
    int s0 = srcs[k];
    float e0 = asrc[s0] + ad; e0 = (e0 > 0.f) ? e0 : 0.2f * e0;
    float w0 = __expf(e0);
    ushort8 r0 = *(const ushort8*)&H2b[(size_t)s0 * HID + j * 8];
    wsum += w0;
    #pragma unroll
    for (int i = 0; i < 8; ++i) acc[i] += w0 * bf2f(r0[i]);
  }
  #pragma unroll
  for (int i = 0; i < 8; ++i) {
    acc[i] += __shfl_xor(acc[i], 8);
    acc[i] += __shfl_xor(acc[i], 16);
    acc[i] += __shfl_xor(acc[i], 32);
  }
  wsum += __shfl_xor(wsum, 8);
  wsum += __shfl_xor(wsum, 16);
  wsum += __shfl_xor(wsum, 32);

  if (q == 0) {
    float inv = 1.f / (wsum + 1e-16f);
    int f = j * 8;
    float o[8];
    #pragma unroll
    for (int i = 0; i < 8; ++i) {
      float val = (acc[i] * inv + b2[f + i] - mu2[f + i]) *
                  (g2[f + i] * rsqrtf(var2[f + i] + 1e-5f)) + be2[f + i];
      o[i] = (val > 0.f) ? val : (__expf(val) - 1.f);
    }
    *(float4*)&out[(size_t)n * HID + f]     = make_float4(o[0], o[1], o[2], o[3]);
    *(float4*)&out[(size_t)n * HID + f + 4] = make_float4(o[4], o[5], o[6], o[7]);
  }
}

// ---------------------------------------------------------------------------

extern "C" void kernel_launch(void* const* d_in, const int* in_sizes, int n_in,
                              void* d_out, int out_size, void* d_ws, size_t ws_size,
                              hipStream_t stream) {
  const float* x      = (const float*)d_in[0];
  const int*   ei     = (const int*)d_in[1];
  const float* W1     = (const float*)d_in[2];
  const float* a_src1 = (const float*)d_in[3];
  const float* a_dst1 = (const float*)d_in[4];
  const float* b1     = (const float*)d_in[5];
  const float* g1     = (const float*)d_in[6];
  const float* be1    = (const float*)d_in[7];
  const float* mu1    = (const float*)d_in[8];
  const float* var1   = (const float*)d_in[9];
  const float* W2     = (const float*)d_in[10];
  const float* a_src2 = (const float*)d_in[11];
  const float* a_dst2 = (const float*)d_in[12];
  const float* b2     = (const float*)d_in[13];
  const float* g2     = (const float*)d_in[14];
  const float* be2    = (const float*)d_in[15];
  const float* mu2    = (const float*)d_in[16];
  const float* var2   = (const float*)d_in[17];
  float* out = (float*)d_out;

  int N = in_sizes[0] / IN_DIM;
  int E = in_sizes[1] / 2;
  int Etot = E + N;
  int NB = (N + 1023) / 1024;

  // Workspace (~60 MB):
  //   H1region[N*256]ushort (fp8 H1 first half; reused as bf16 H2b) |
  //   X2b[N*256]b | W1t[256*256]b | W2t[64*256]b | w1[4*Etot]f |
  //   asrc1[4N]f | adst1[4N]f | asrc2[N]f | adst2[N]f | counts[N] |
  //   indptr[N+1] | blocksums[NB] | blockoff[NB+1] | done[1] | rank[Etot] |
  //   srcs[Etot]
  unsigned short* H1region = (unsigned short*)d_ws;
  unsigned char*  H1f8 = (unsigned char*)H1region;
  unsigned short* X2b = H1region + (size_t)N * C1;
  unsigned short* W1t = X2b + (size_t)N * C1;
  unsigned short* W2t = W1t + 256 * 256;
  float* w1    = (float*)(W2t + 64 * 256);
  float* asrc1 = w1 + (size_t)4 * Etot;
  float* adst1 = asrc1 + (size_t)N * HEADS;
  float* asrc2 = adst1 + (size_t)N * HEADS;
  float* adst2 = asrc2 + N;
  int* counts    = (int*)(adst2 + N);
  int* indptr    = counts + N;
  int* blocksums = indptr + (N + 1);
  int* blockoff  = blocksums + NB;
  int* done      = blockoff + (NB + 1);
  int* rank      = done + 1;
  int* srcs      = rank + Etot;
  unsigned short* H2b = H1region;   // H1 fp8 dead after gat1_agg

  // --- prep + CSR build (rank trick) ---
  prep_kernel<<<(256 * 256 + 64 * 256 + N + 255) / 256, 256, 0, stream>>>(
      W1, W1t, W2, W2t, counts, done, N);
  hist_kernel<<<(Etot + 255) / 256, 256, 0, stream>>>(ei, E, N, counts, rank);
  scan12_kernel<<<NB, 256, 0, stream>>>(counts, blocksums, blockoff, done, N, NB);
  scan3_kernel<<<NB, 256, 0, stream>>>(counts, blockoff, indptr, N, NB);

  // --- Layer 1 ---
  gemm1_fused<<<(N + 127) / 128, 512, 0, stream>>>(x, W1t, H1f8, a_src1, a_dst1,
                                                   asrc1, adst1, N);
  fillw_kernel<<<(Etot + 255) / 256, 256, 0, stream>>>(ei, E, N, indptr, rank, srcs,
                                                       asrc1, adst1, w1);
  gat1_agg<<<(N + 3) / 4, 256, 0, stream>>>(H1f8, w1, indptr, srcs,
                                            b1, g1, be1, mu1, var1, X2b, N);

  // --- Layer 2 ---
  gemm2_fused<<<(N + 63) / 64, 256, 0, stream>>>(X2b, W2t, H2b, a_src2, a_dst2,
                                                 asrc2, adst2, N);
  gat2_agg<<<(N + 3) / 4, 256, 0, stream>>>(H2b, asrc2, adst2, indptr, srcs,
                                            b2, g2, be2, mu2, var2, out, N);
}

// Round 18
// 198.629 us; speedup vs baseline: 1.0365x; 1.0365x over previous
//
#include <hip/hip_runtime.h>

#define IN_DIM 256
#define HID 64
#define HEADS 4
#define C1 256   // HID*HEADS

typedef __attribute__((ext_vector_type(4))) float  f32x4;
typedef __attribute__((ext_vector_type(2))) float  f32x2;
typedef __attribute__((ext_vector_type(8))) short  short8;
typedef __attribute__((ext_vector_type(8))) unsigned short ushort8;
typedef __attribute__((ext_vector_type(4))) unsigned short ushort4v;

static __device__ __forceinline__ unsigned short f2bf(float f) {
  union { float f; unsigned int u; } v; v.f = f;
  unsigned int r = v.u + 0x7fffu + ((v.u >> 16) & 1u);   // RNE
  return (unsigned short)(r >> 16);
}
static __device__ __forceinline__ float bf2f(unsigned short u) {
  union { unsigned int u; float f; } v; v.u = ((unsigned int)u) << 16;
  return v.f;
}
static __device__ __forceinline__ unsigned char f2fp8(float f) {
  unsigned int p = __builtin_amdgcn_cvt_pk_fp8_f32(f, f, 0u, false);
  return (unsigned char)(p & 0xFFu);
}

// ---------------------------------------------------------------------------
// prep: weight transposes (f32 -> bf16, [k][n] -> [n][k]) + zero counts/done
// ---------------------------------------------------------------------------

__global__ __launch_bounds__(256) void prep_kernel(const float* __restrict__ W1,
                                                   unsigned short* __restrict__ W1t,
                                                   const float* __restrict__ W2,
                                                   unsigned short* __restrict__ W2t,
                                                   int* __restrict__ counts,
                                                   int* __restrict__ done, int N) {
  int t = blockIdx.x * 256 + threadIdx.x;
  if (t == 0) *done = 0;
  if (t < 256 * 256) {
    int k = t & 255, n = t >> 8;
    W1t[n * 256 + k] = f2bf(W1[k * 256 + n]);
  } else if (t < 256 * 256 + 64 * 256) {
    int u = t - 256 * 256;
    int k = u & 255, n = u >> 8;
    W2t[n * 256 + k] = f2bf(W2[k * 64 + n]);
  } else {
    int i = t - (256 * 256 + 64 * 256);
    if (i < N) counts[i] = 0;
  }
}

// ---------------------------------------------------------------------------
// CSR build — rank trick
// ---------------------------------------------------------------------------

__global__ __launch_bounds__(256) void hist_kernel(const int* __restrict__ ei,
                                                   int E, int N,
                                                   int* __restrict__ counts,
                                                   int* __restrict__ rank) {
  int e = blockIdx.x * 256 + threadIdx.x;
  if (e >= E + N) return;
  int dst = (e < E) ? ei[(size_t)E + e] : (e - E);
  rank[e] = atomicAdd(&counts[dst], 1);
}

__global__ __launch_bounds__(256) void scan12_kernel(const int* __restrict__ counts,
                                                     int* __restrict__ blocksums,
                                                     int* __restrict__ blockoff,
                                                     int* __restrict__ done,
                                                     int N, int NB) {
  int tid = threadIdx.x;
  int base = blockIdx.x * 1024 + tid * 4;
  int s = 0;
  if (base + 3 < N) {
    int4 v = *(const int4*)&counts[base];
    s = v.x + v.y + v.z + v.w;
  } else {
    for (int i = 0; i < 4; ++i) if (base + i < N) s += counts[base + i];
  }
  __shared__ int red[256];
  red[tid] = s;
  __syncthreads();
  for (int off = 128; off; off >>= 1) {
    if (tid < off) red[tid] += red[tid + off];
    __syncthreads();
  }
  __shared__ int amLast;
  if (tid == 0) {
    blocksums[blockIdx.x] = red[0];
    __threadfence();
    amLast = (atomicAdd(done, 1) == NB - 1);
  }
  __syncthreads();
  if (amLast && tid < 64) {
    __threadfence();
    int lane = tid;
    int carry = 0;
    for (int b = 0; b < NB; b += 64) {
      int v = (b + lane < NB) ? blocksums[b + lane] : 0;
      int incl = v;
      #pragma unroll
      for (int off = 1; off < 64; off <<= 1) {
        int t = __shfl_up(incl, off);
        if (lane >= off) incl += t;
      }
      if (b + lane < NB) blockoff[b + lane] = carry + incl - v;
      carry += __shfl(incl, 63);
    }
    if (lane == 0) blockoff[NB] = carry;
  }
}

__global__ __launch_bounds__(256) void scan3_kernel(const int* __restrict__ counts,
                                                    const int* __restrict__ blockoff,
                                                    int* __restrict__ indptr, int N, int NB) {
  int tid = threadIdx.x;
  int base = blockIdx.x * 1024 + tid * 4;
  int c0 = 0, c1 = 0, c2 = 0, c3 = 0;
  if (base + 3 < N) {
    int4 v = *(const int4*)&counts[base];
    c0 = v.x; c1 = v.y; c2 = v.z; c3 = v.w;
  } else {
    if (base + 0 < N) c0 = counts[base + 0];
    if (base + 1 < N) c1 = counts[base + 1];
    if (base + 2 < N) c2 = counts[base + 2];
    if (base + 3 < N) c3 = counts[base + 3];
  }
  int s = c0 + c1 + c2 + c3;
  __shared__ int sc[256];
  sc[tid] = s;
  __syncthreads();
  for (int off = 1; off < 256; off <<= 1) {
    int t = (tid >= off) ? sc[tid - off] : 0;
    __syncthreads();
    sc[tid] += t;
    __syncthreads();
  }
  int p = sc[tid] - s + blockoff[blockIdx.x];
  if (base + 0 < N) { indptr[base + 0] = p; p += c0; }
  if (base + 1 < N) { indptr[base + 1] = p; p += c1; }
  if (base + 2 < N) { indptr[base + 2] = p; p += c2; }
  if (base + 3 < N) { indptr[base + 3] = p; p += c3; }
  if (blockIdx.x == 0 && tid == 0) indptr[N] = blockoff[NB];
}

// fill (atomic-free via rank) fused with layer-1 edge weights.
__global__ __launch_bounds__(256) void fillw_kernel(const int* __restrict__ ei, int E, int N,
                                                    const int* __restrict__ indptr,
                                                    const int* __restrict__ rank,
                                                    int* __restrict__ srcs,
                                                    const float* __restrict__ asrc,
                                                    const float* __restrict__ adst,
                                                    float* __restrict__ w) {
  int e = blockIdx.x * 256 + threadIdx.x;
  if (e >= E + N) return;
  int src, dst;
  if (e < E) { src = ei[e]; dst = ei[(size_t)E + e]; }
  else       { src = e - E; dst = e - E; }
  int pos = indptr[dst] + rank[e];
  srcs[pos] = src;
  float4 as = *(const float4*)&asrc[src * 4];
  float4 ad = *(const float4*)&adst[dst * 4];
  float e0 = as.x + ad.x; e0 = (e0 > 0.f) ? e0 : 0.2f * e0;
  float e1 = as.y + ad.y; e1 = (e1 > 0.f) ? e1 : 0.2f * e1;
  float e2 = as.z + ad.z; e2 = (e2 > 0.f) ? e2 : 0.2f * e2;
  float e3 = as.w + ad.w; e3 = (e3 > 0.f) ? e3 : 0.2f * e3;
  *(float4*)&w[pos * 4] = make_float4(__expf(e0), __expf(e1), __expf(e2), __expf(e3));
}

// ---------------------------------------------------------------------------
// gemm1 fused: H1f8[M,256](fp8 e4m3) = x[M,256](f32) @ W1t^T, alpha1 epilogue.
// BM=128, BN=256, BK=32; 512 threads; LDT3=56; LDS 43KB -> 3 blocks/CU.
// ---------------------------------------------------------------------------

#define LDT2 72   // gemm2 pad
#define LDT3 56   // gemm1 pad (BK=32)

__global__ __launch_bounds__(512) void gemm1_fused(const float* __restrict__ A,
                                                   const unsigned short* __restrict__ Bt,
                                                   unsigned char* __restrict__ C,
                                                   const float* __restrict__ a_src,
                                                   const float* __restrict__ a_dst,
                                                   float* __restrict__ asrc,
                                                   float* __restrict__ adst, int M) {
  const int K = 256;
  __shared__ unsigned short As[128 * LDT3];
  __shared__ unsigned short Bs[256 * LDT3];
  int bm = blockIdx.x * 128;
  int tid = threadIdx.x;
  int wid = tid >> 6, lane = tid & 63;
  int wr = (wid >> 1) * 32, wc = (wid & 1) * 128;
  int l15 = lane & 15, lq = lane >> 4;

  f32x4 acc[2][8];
  #pragma unroll
  for (int i = 0; i < 2; ++i)
    #pragma unroll
    for (int f = 0; f < 8; ++f) acc[i][f] = (f32x4){0,0,0,0};

  for (int k0 = 0; k0 < K; k0 += 32) {
    {
      int r = tid >> 2, c = (tid & 3) * 8;
      int row = bm + r;
      float4 v0 = make_float4(0.f,0.f,0.f,0.f), v1 = v0;
      if (row < M) {
        v0 = *(const float4*)&A[(size_t)row * K + k0 + c];
        v1 = *(const float4*)&A[(size_t)row * K + k0 + c + 4];
      }
      ushort8 o;
      o[0]=f2bf(v0.x); o[1]=f2bf(v0.y); o[2]=f2bf(v0.z); o[3]=f2bf(v0.w);
      o[4]=f2bf(v1.x); o[5]=f2bf(v1.y); o[6]=f2bf(v1.z); o[7]=f2bf(v1.w);
      *(ushort8*)&As[r * LDT3 + c] = o;
    }
    {
      int r = tid >> 1, seg = (tid & 1) * 16;
      ushort8 v0 = *(const ushort8*)&Bt[(size_t)r * K + k0 + seg];
      ushort8 v1 = *(const ushort8*)&Bt[(size_t)r * K + k0 + seg + 8];
      *(ushort8*)&Bs[r * LDT3 + seg]     = v0;
      *(ushort8*)&Bs[r * LDT3 + seg + 8] = v1;
    }
    __syncthreads();

    short8 a0 = *(const short8*)&As[(wr + l15) * LDT3 + lq * 8];
    short8 a1 = *(const short8*)&As[(wr + 16 + l15) * LDT3 + lq * 8];
    #pragma unroll
    for (int f = 0; f < 8; ++f) {
      short8 b = *(const short8*)&Bs[(wc + f * 16 + l15) * LDT3 + lq * 8];
      acc[0][f] = __builtin_amdgcn_mfma_f32_16x16x32_bf16(a0, b, acc[0][f], 0, 0, 0);
      acc[1][f] = __builtin_amdgcn_mfma_f32_16x16x32_bf16(a1, b, acc[1][f], 0, 0, 0);
    }
    __syncthreads();
  }

  #pragma unroll
  for (int r = 0; r < 4; ++r) {
    int row0 = bm + wr + lq * 4 + r;
    int row1 = row0 + 16;
    #pragma unroll
    for (int f = 0; f < 8; ++f) {
      int col = wc + f * 16 + l15;
      if (row0 < M) C[(size_t)row0 * 256 + col] = f2fp8(acc[0][f][r]);
      if (row1 < M) C[(size_t)row1 * 256 + col] = f2fp8(acc[1][f][r]);
    }
  }

  float ps[2][4][2], pd[2][4][2];
  #pragma unroll
  for (int i = 0; i < 2; ++i)
    #pragma unroll
    for (int r = 0; r < 4; ++r) { ps[i][r][0]=0.f; ps[i][r][1]=0.f; pd[i][r][0]=0.f; pd[i][r][1]=0.f; }
  #pragma unroll
  for (int f = 0; f < 8; ++f) {
    int col = wc + f * 16 + l15;
    float av = a_src[col], dv = a_dst[col];
    int hh = f >> 2;
    #pragma unroll
    for (int i = 0; i < 2; ++i)
      #pragma unroll
      for (int r = 0; r < 4; ++r) {
        ps[i][r][hh] += acc[i][f][r] * av;
        pd[i][r][hh] += acc[i][f][r] * dv;
      }
  }
  #pragma unroll
  for (int off = 1; off < 16; off <<= 1) {
    #pragma unroll
    for (int i = 0; i < 2; ++i)
      #pragma unroll
      for (int r = 0; r < 4; ++r) {
        ps[i][r][0] += __shfl_xor(ps[i][r][0], off);
        ps[i][r][1] += __shfl_xor(ps[i][r][1], off);
        pd[i][r][0] += __shfl_xor(pd[i][r][0], off);
        pd[i][r][1] += __shfl_xor(pd[i][r][1], off);
      }
  }
  if (l15 == 0) {
    int hb = wc >> 6;
    #pragma unroll
    for (int i = 0; i < 2; ++i)
      #pragma unroll
      for (int r = 0; r < 4; ++r) {
        int row = bm + wr + lq * 4 + r + i * 16;
        if (row < M) {
          asrc[row * 4 + hb]     = ps[i][r][0];
          asrc[row * 4 + hb + 1] = ps[i][r][1];
          adst[row * 4 + hb]     = pd[i][r][0];
          adst[row * 4 + hb + 1] = pd[i][r][1];
        }
      }
  }
}

// ---------------------------------------------------------------------------
// gemm2 fused: H2b[M,64](bf16) = X2b[M,256](bf16) @ W2t^T, alpha2 in epilogue.
// ---------------------------------------------------------------------------

__global__ __launch_bounds__(256) void gemm2_fused(const unsigned short* __restrict__ A,
                                                   const unsigned short* __restrict__ Bt,
                                                   unsigned short* __restrict__ C,
                                                   const float* __restrict__ a_src,
                                                   const float* __restrict__ a_dst,
                                                   float* __restrict__ asrc,
                                                   float* __restrict__ adst, int M) {
  const int K = 256;
  __shared__ unsigned short As[64 * LDT2];
  __shared__ unsigned short Bs[64 * LDT2];
  __shared__ float sred[64], dred[64];
  int bm = blockIdx.x * 64;
  int tid = threadIdx.x;
  int wid = tid >> 6, lane = tid & 63;
  int wr = (wid >> 1) * 32, wc = (wid & 1) * 32;
  int l15 = lane & 15, lq = lane >> 4;

  f32x4 acc[2][2];
  #pragma unroll
  for (int i = 0; i < 2; ++i) { acc[i][0] = (f32x4){0,0,0,0}; acc[i][1] = (f32x4){0,0,0,0}; }

  for (int k0 = 0; k0 < K; k0 += 64) {
    {
      int r = tid >> 2, seg = (tid & 3) * 16;
      int row = bm + r;
      ushort8 v0 = {0,0,0,0,0,0,0,0}, v1 = {0,0,0,0,0,0,0,0};
      if (row < M) {
        v0 = *(const ushort8*)&A[(size_t)row * K + k0 + seg];
        v1 = *(const ushort8*)&A[(size_t)row * K + k0 + seg + 8];
      }
      *(ushort8*)&As[r * LDT2 + seg]     = v0;
      *(ushort8*)&As[r * LDT2 + seg + 8] = v1;
    }
    {
      int r = tid >> 2, seg = (tid & 3) * 16;
      ushort8 v0 = *(const ushort8*)&Bt[(size_t)r * K + k0 + seg];
      ushort8 v1 = *(const ushort8*)&Bt[(size_t)r * K + k0 + seg + 8];
      *(ushort8*)&Bs[r * LDT2 + seg]     = v0;
      *(ushort8*)&Bs[r * LDT2 + seg + 8] = v1;
    }
    __syncthreads();

    #pragma unroll
    for (int ks = 0; ks < 2; ++ks) {
      short8 a0 = *(const short8*)&As[(wr + l15) * LDT2 + ks * 32 + lq * 8];
      short8 a1 = *(const short8*)&As[(wr + 16 + l15) * LDT2 + ks * 32 + lq * 8];
      #pragma unroll
      for (int f = 0; f < 2; ++f) {
        short8 b = *(const short8*)&Bs[(wc + f * 16 + l15) * LDT2 + ks * 32 + lq * 8];
        acc[0][f] = __builtin_amdgcn_mfma_f32_16x16x32_bf16(a0, b, acc[0][f], 0, 0, 0);
        acc[1][f] = __builtin_amdgcn_mfma_f32_16x16x32_bf16(a1, b, acc[1][f], 0, 0, 0);
      }
    }
    __syncthreads();
  }

  #pragma unroll
  for (int r = 0; r < 4; ++r) {
    int row0 = bm + wr + lq * 4 + r;
    int row1 = row0 + 16;
    #pragma unroll
    for (int f = 0; f < 2; ++f) {
      int col = wc + f * 16 + l15;
      if (row0 < M) C[(size_t)row0 * 64 + col] = f2bf(acc[0][f][r]);
      if (row1 < M) C[(size_t)row1 * 64 + col] = f2bf(acc[1][f][r]);
    }
  }

  float ps[2][4], pd[2][4];
  #pragma unroll
  for (int i = 0; i < 2; ++i)
    #pragma unroll
    for (int r = 0; r < 4; ++r) { ps[i][r] = 0.f; pd[i][r] = 0.f; }
  #pragma unroll
  for (int f = 0; f < 2; ++f) {
    int col = wc + f * 16 + l15;
    float av = a_src[col], dv = a_dst[col];
    #pragma unroll
    for (int i = 0; i < 2; ++i)
      #pragma unroll
      for (int r = 0; r < 4; ++r) {
        ps[i][r] += acc[i][f][r] * av;
        pd[i][r] += acc[i][f][r] * dv;
      }
  }
  #pragma unroll
  for (int off = 1; off < 16; off <<= 1) {
    #pragma unroll
    for (int i = 0; i < 2; ++i)
      #pragma unroll
      for (int r = 0; r < 4; ++r) {
        ps[i][r] += __shfl_xor(ps[i][r], off);
        pd[i][r] += __shfl_xor(pd[i][r], off);
      }
  }
  if ((wid & 1) == 0 && l15 == 0) {
    #pragma unroll
    for (int i = 0; i < 2; ++i)
      #pragma unroll
      for (int r = 0; r < 4; ++r) {
        int rl = wr + lq * 4 + r + i * 16;
        sred[rl] = ps[i][r];
        dred[rl] = pd[i][r];
      }
  }
  __syncthreads();
  if ((wid & 1) == 1 && l15 == 0) {
    #pragma unroll
    for (int i = 0; i < 2; ++i)
      #pragma unroll
      for (int r = 0; r < 4; ++r) {
        int rl = wr + lq * 4 + r + i * 16;
        int row = bm + rl;
        if (row < M) {
          asrc[row] = sred[rl] + ps[i][r];
          adst[row] = dred[rl] + pd[i][r];
        }
      }
  }
}

// ---------------------------------------------------------------------------
// GAT agg layer 1 (fp8 H1): split-wave (2 edges), 8B/lane, 4x unroll,
// packed f32x2 accumulators. 512-thread blocks (8 nodes/block).
// ---------------------------------------------------------------------------

__global__ __launch_bounds__(512) void gat1_agg(const unsigned char* __restrict__ H1f8,
                                                const float* __restrict__ w,
                                                const int* __restrict__ indptr,
                                                const int* __restrict__ srcs,
                                                const float* __restrict__ b1,
                                                const float* __restrict__ g1,
                                                const float* __restrict__ be1,
                                                const float* __restrict__ mu1,
                                                const float* __restrict__ var1,
                                                unsigned short* __restrict__ X2b, int N) {
  int n = blockIdx.x * 8 + (threadIdx.x >> 6);
  if (n >= N) return;
  int lane = threadIdx.x & 63;
  int half = lane >> 5;
  int j = lane & 31;
  int h = j >> 3;
  int start = indptr[n], end = indptr[n + 1];

  f32x2 acc2[4];
  #pragma unroll
  for (int i = 0; i < 4; ++i) acc2[i] = (f32x2){0.f, 0.f};
  float wsum = 0.f;
  int k = start + half;
  for (; k + 6 < end; k += 8) {
    int s0 = srcs[k], s1 = srcs[k + 2], s2 = srcs[k + 4], s3 = srcs[k + 6];
    float w0 = w[k * 4 + h], w1v = w[(k + 2) * 4 + h];
    float w2v = w[(k + 4) * 4 + h], w3v = w[(k + 6) * 4 + h];
    uint2 u0 = *(const uint2*)&H1f8[(size_t)s0 * C1 + j * 8];
    uint2 u1 = *(const uint2*)&H1f8[(size_t)s1 * C1 + j * 8];
    uint2 u2 = *(const uint2*)&H1f8[(size_t)s2 * C1 + j * 8];
    uint2 u3 = *(const uint2*)&H1f8[(size_t)s3 * C1 + j * 8];
    wsum += (w0 + w1v) + (w2v + w3v);
    {
      f32x2 wv = (f32x2){w0, w0};
      acc2[0] += wv * __builtin_amdgcn_cvt_pk_f32_fp8(u0.x, false);
      acc2[1] += wv * __builtin_amdgcn_cvt_pk_f32_fp8(u0.x, true);
      acc2[2] += wv * __builtin_amdgcn_cvt_pk_f32_fp8(u0.y, false);
      acc2[3] += wv * __builtin_amdgcn_cvt_pk_f32_fp8(u0.y, true);
    }
    {
      f32x2 wv = (f32x2){w1v, w1v};
      acc2[0] += wv * __builtin_amdgcn_cvt_pk_f32_fp8(u1.x, false);
      acc2[1] += wv * __builtin_amdgcn_cvt_pk_f32_fp8(u1.x, true);
      acc2[2] += wv * __builtin_amdgcn_cvt_pk_f32_fp8(u1.y, false);
      acc2[3] += wv * __builtin_amdgcn_cvt_pk_f32_fp8(u1.y, true);
    }
    {
      f32x2 wv = (f32x2){w2v, w2v};
      acc2[0] += wv * __builtin_amdgcn_cvt_pk_f32_fp8(u2.x, false);
      acc2[1] += wv * __builtin_amdgcn_cvt_pk_f32_fp8(u2.x, true);
      acc2[2] += wv * __builtin_amdgcn_cvt_pk_f32_fp8(u2.y, false);
      acc2[3] += wv * __builtin_amdgcn_cvt_pk_f32_fp8(u2.y, true);
    }
    {
      f32x2 wv = (f32x2){w3v, w3v};
      acc2[0] += wv * __builtin_amdgcn_cvt_pk_f32_fp8(u3.x, false);
      acc2[1] += wv * __builtin_amdgcn_cvt_pk_f32_fp8(u3.x, true);
      acc2[2] += wv * __builtin_amdgcn_cvt_pk_f32_fp8(u3.y, false);
      acc2[3] += wv * __builtin_amdgcn_cvt_pk_f32_fp8(u3.y, true);
    }
  }
  for (; k < end; k += 2) {
    int s0 = srcs[k];
    float w0 = w[k * 4 + h];
    uint2 u0 = *(const uint2*)&H1f8[(size_t)s0 * C1 + j * 8];
    wsum += w0;
    f32x2 wv = (f32x2){w0, w0};
    acc2[0] += wv * __builtin_amdgcn_cvt_pk_f32_fp8(u0.x, false);
    acc2[1] += wv * __builtin_amdgcn_cvt_pk_f32_fp8(u0.x, true);
    acc2[2] += wv * __builtin_amdgcn_cvt_pk_f32_fp8(u0.y, false);
    acc2[3] += wv * __builtin_amdgcn_cvt_pk_f32_fp8(u0.y, true);
  }
  float acc[8];
  #pragma unroll
  for (int i = 0; i < 4; ++i) { acc[2*i] = acc2[i][0]; acc[2*i+1] = acc2[i][1]; }
  #pragma unroll
  for (int i = 0; i < 8; ++i) acc[i] += __shfl_xor(acc[i], 32);
  wsum += __shfl_xor(wsum, 32);

  if (half == 0) {
    float inv = 1.f / (wsum + 1e-16f);
    int f = j * 8;
    ushort8 o;
    #pragma unroll
    for (int i = 0; i < 8; ++i) {
      float val = (acc[i] * inv + b1[f + i] - mu1[f + i]) *
                  (g1[f + i] * rsqrtf(var1[f + i] + 1e-5f)) + be1[f + i];
      val = (val > 0.f) ? val : (__expf(val) - 1.f);
      o[i] = f2bf(val);
    }
    *(ushort8*)&X2b[(size_t)n * C1 + f] = o;
  }
}

// ---------------------------------------------------------------------------
// GAT agg layer 2 (fused edge weights, 8-slot geometry): 512-thread blocks,
// 8 nodes/block, 8 edge slots, 16B/lane, 2x unroll; w inline from asrc2.
// ---------------------------------------------------------------------------

__global__ __launch_bounds__(512) void gat2_agg(const unsigned short* __restrict__ H2b,
                                                const float* __restrict__ asrc,
                                                const float* __restrict__ adst,
                                                const int* __restrict__ indptr,
                                                const int* __restrict__ srcs,
                                                const float* __restrict__ b2,
                                                const float* __restrict__ g2,
                                                const float* __restrict__ be2,
                                                const float* __restrict__ mu2,
                                                const float* __restrict__ var2,
                                                float* __restrict__ out, int N) {
  int n = blockIdx.x * 8 + (threadIdx.x >> 6);
  if (n >= N) return;
  int lane = threadIdx.x & 63;
  int q = lane >> 3;
  int j = lane & 7;
  int start = indptr[n], end = indptr[n + 1];
  float ad = adst[n];

  float acc[8];
  #pragma unroll
  for (int i = 0; i < 8; ++i) acc[i] = 0.f;
  float wsum = 0.f;

  int k = start + q;
  for (; k + 8 < end; k += 16) {
    int s0 = srcs[k], s1 = srcs[k + 8];
    float e0 = asrc[s0] + ad; e0 = (e0 > 0.f) ? e0 : 0.2f * e0;
    float e1 = asrc[s1] + ad; e1 = (e1 > 0.f) ? e1 : 0.2f * e1;
    float w0 = __expf(e0), w1v = __expf(e1);
    ushort8 r0 = *(const ushort8*)&H2b[(size_t)s0 * HID + j * 8];
    ushort8 r1 = *(const ushort8*)&H2b[(size_t)s1 * HID + j * 8];
    wsum += w0 + w1v;
    #pragma unroll
    for (int i = 0; i < 8; ++i)
      acc[i] += w0 * bf2f(r0[i]) + w1v * bf2f(r1[i]);
  }
  if (k < end) {
    int s0 = srcs[k];
    float e0 = asrc[s0] + ad; e0 = (e0 > 0.f) ? e0 : 0.2f * e0;
    float w0 = __expf(e0);
    ushort8 r0 = *(const ushort8*)&H2b[(size_t)s0 * HID + j * 8];
    wsum += w0;
    #pragma unroll
    for (int i = 0; i < 8; ++i) acc[i] += w0 * bf2f(r0[i]);
  }
  #pragma unroll
  for (int i = 0; i < 8; ++i) {
    acc[i] += __shfl_xor(acc[i], 8);
    acc[i] += __shfl_xor(acc[i], 16);
    acc[i] += __shfl_xor(acc[i], 32);
  }
  wsum += __shfl_xor(wsum, 8);
  wsum += __shfl_xor(wsum, 16);
  wsum += __shfl_xor(wsum, 32);

  if (q == 0) {
    float inv = 1.f / (wsum + 1e-16f);
    int f = j * 8;
    float o[8];
    #pragma unroll
    for (int i = 0; i < 8; ++i) {
      float val = (acc[i] * inv + b2[f + i] - mu2[f + i]) *
                  (g2[f + i] * rsqrtf(var2[f + i] + 1e-5f)) + be2[f + i];
      o[i] = (val > 0.f) ? val : (__expf(val) - 1.f);
    }
    *(float4*)&out[(size_t)n * HID + f]     = make_float4(o[0], o[1], o[2], o[3]);
    *(float4*)&out[(size_t)n * HID + f + 4] = make_float4(o[4], o[5], o[6], o[7]);
  }
}

// ---------------------------------------------------------------------------

extern "C" void kernel_launch(void* const* d_in, const int* in_sizes, int n_in,
                              void* d_out, int out_size, void* d_ws, size_t ws_size,
                              hipStream_t stream) {
  const float* x      = (const float*)d_in[0];
  const int*   ei     = (const int*)d_in[1];
  const float* W1     = (const float*)d_in[2];
  const float* a_src1 = (const float*)d_in[3];
  const float* a_dst1 = (const float*)d_in[4];
  const float* b1     = (const float*)d_in[5];
  const float* g1     = (const float*)d_in[6];
  const float* be1    = (const float*)d_in[7];
  const float* mu1    = (const float*)d_in[8];
  const float* var1   = (const float*)d_in[9];
  const float* W2     = (const float*)d_in[10];
  const float* a_src2 = (const float*)d_in[11];
  const float* a_dst2 = (const float*)d_in[12];
  const float* b2     = (const float*)d_in[13];
  const float* g2     = (const float*)d_in[14];
  const float* be2    = (const float*)d_in[15];
  const float* mu2    = (const float*)d_in[16];
  const float* var2   = (const float*)d_in[17];
  float* out = (float*)d_out;

  int N = in_sizes[0] / IN_DIM;
  int E = in_sizes[1] / 2;
  int Etot = E + N;
  int NB = (N + 1023) / 1024;

  unsigned short* H1region = (unsigned short*)d_ws;
  unsigned char*  H1f8 = (unsigned char*)H1region;
  unsigned short* X2b = H1region + (size_t)N * C1;
  unsigned short* W1t = X2b + (size_t)N * C1;
  unsigned short* W2t = W1t + 256 * 256;
  float* w1    = (float*)(W2t + 64 * 256);
  float* asrc1 = w1 + (size_t)4 * Etot;
  float* adst1 = asrc1 + (size_t)N * HEADS;
  float* asrc2 = adst1 + (size_t)N * HEADS;
  float* adst2 = asrc2 + N;
  int* counts    = (int*)(adst2 + N);
  int* indptr    = counts + N;
  int* blocksums = indptr + (N + 1);
  int* blockoff  = blocksums + NB;
  int* done      = blockoff + (NB + 1);
  int* rank      = done + 1;
  int* srcs      = rank + Etot;
  unsigned short* H2b = H1region;   // H1 fp8 dead after gat1_agg

  // --- prep + CSR build (rank trick) ---
  prep_kernel<<<(256 * 256 + 64 * 256 + N + 255) / 256, 256, 0, stream>>>(
      W1, W1t, W2, W2t, counts, done, N);
  hist_kernel<<<(Etot + 255) / 256, 256, 0, stream>>>(ei, E, N, counts, rank);
  scan12_kernel<<<NB, 256, 0, stream>>>(counts, blocksums, blockoff, done, N, NB);
  scan3_kernel<<<NB, 256, 0, stream>>>(counts, blockoff, indptr, N, NB);

  // --- Layer 1 ---
  gemm1_fused<<<(N + 127) / 128, 512, 0, stream>>>(x, W1t, H1f8, a_src1, a_dst1,
                                                   asrc1, adst1, N);
  fillw_kernel<<<(Etot + 255) / 256, 256, 0, stream>>>(ei, E, N, indptr, rank, srcs,
                                                       asrc1, adst1, w1);
  gat1_agg<<<(N + 7) / 8, 512, 0, stream>>>(H1f8, w1, indptr, srcs,
                                            b1, g1, be1, mu1, var1, X2b, N);

  // --- Layer 2 ---
  gemm2_fused<<<(N + 63) / 64, 256, 0, stream>>>(X2b, W2t, H2b, a_src2, a_dst2,
                                                 asrc2, adst2, N);
  gat2_agg<<<(N + 7) / 8, 512, 0, stream>>>(H2b, asrc2, adst2, indptr, srcs,
                                            b2, g2, be2, mu2, var2, out, N);
}

// Round 19
// 192.731 us; speedup vs baseline: 1.0682x; 1.0306x over previous
//
#include <hip/hip_runtime.h>

#define IN_DIM 256
#define HID 64
#define HEADS 4
#define C1 256   // HID*HEADS

typedef __attribute__((ext_vector_type(4))) float  f32x4;
typedef __attribute__((ext_vector_type(2))) float  f32x2;
typedef __attribute__((ext_vector_type(8))) short  short8;
typedef __attribute__((ext_vector_type(8))) unsigned short ushort8;
typedef __attribute__((ext_vector_type(4))) unsigned short ushort4v;

static __device__ __forceinline__ unsigned short f2bf(float f) {
  union { float f; unsigned int u; } v; v.f = f;
  unsigned int r = v.u + 0x7fffu + ((v.u >> 16) & 1u);   // RNE
  return (unsigned short)(r >> 16);
}
static __device__ __forceinline__ float bf2f(unsigned short u) {
  union { unsigned int u; float f; } v; v.u = ((unsigned int)u) << 16;
  return v.f;
}
static __device__ __forceinline__ unsigned char f2fp8(float f) {
  unsigned int p = __builtin_amdgcn_cvt_pk_fp8_f32(f, f, 0u, false);
  return (unsigned char)(p & 0xFFu);
}

// ---------------------------------------------------------------------------
// prep: weight transposes (f32 -> bf16, [k][n] -> [n][k]) + zero counts/done
// ---------------------------------------------------------------------------

__global__ __launch_bounds__(256) void prep_kernel(const float* __restrict__ W1,
                                                   unsigned short* __restrict__ W1t,
                                                   const float* __restrict__ W2,
                                                   unsigned short* __restrict__ W2t,
                                                   int* __restrict__ counts,
                                                   int* __restrict__ done, int N) {
  int t = blockIdx.x * 256 + threadIdx.x;
  if (t == 0) *done = 0;
  if (t < 256 * 256) {
    int k = t & 255, n = t >> 8;
    W1t[n * 256 + k] = f2bf(W1[k * 256 + n]);
  } else if (t < 256 * 256 + 64 * 256) {
    int u = t - 256 * 256;
    int k = u & 255, n = u >> 8;
    W2t[n * 256 + k] = f2bf(W2[k * 64 + n]);
  } else {
    int i = t - (256 * 256 + 64 * 256);
    if (i < N) counts[i] = 0;
  }
}

// ---------------------------------------------------------------------------
// CSR build — rank trick
// ---------------------------------------------------------------------------

__global__ __launch_bounds__(256) void hist_kernel(const int* __restrict__ ei,
                                                   int E, int N,
                                                   int* __restrict__ counts,
                                                   int* __restrict__ rank) {
  int e = blockIdx.x * 256 + threadIdx.x;
  if (e >= E + N) return;
  int dst = (e < E) ? ei[(size_t)E + e] : (e - E);
  rank[e] = atomicAdd(&counts[dst], 1);
}

__global__ __launch_bounds__(256) void scan12_kernel(const int* __restrict__ counts,
                                                     int* __restrict__ blocksums,
                                                     int* __restrict__ blockoff,
                                                     int* __restrict__ done,
                                                     int N, int NB) {
  int tid = threadIdx.x;
  int base = blockIdx.x * 1024 + tid * 4;
  int s = 0;
  if (base + 3 < N) {
    int4 v = *(const int4*)&counts[base];
    s = v.x + v.y + v.z + v.w;
  } else {
    for (int i = 0; i < 4; ++i) if (base + i < N) s += counts[base + i];
  }
  __shared__ int red[256];
  red[tid] = s;
  __syncthreads();
  for (int off = 128; off; off >>= 1) {
    if (tid < off) red[tid] += red[tid + off];
    __syncthreads();
  }
  __shared__ int amLast;
  if (tid == 0) {
    blocksums[blockIdx.x] = red[0];
    __threadfence();
    amLast = (atomicAdd(done, 1) == NB - 1);
  }
  __syncthreads();
  if (amLast && tid < 64) {
    __threadfence();
    int lane = tid;
    int carry = 0;
    for (int b = 0; b < NB; b += 64) {
      int v = (b + lane < NB) ? blocksums[b + lane] : 0;
      int incl = v;
      #pragma unroll
      for (int off = 1; off < 64; off <<= 1) {
        int t = __shfl_up(incl, off);
        if (lane >= off) incl += t;
      }
      if (b + lane < NB) blockoff[b + lane] = carry + incl - v;
      carry += __shfl(incl, 63);
    }
    if (lane == 0) blockoff[NB] = carry;
  }
}

__global__ __launch_bounds__(256) void scan3_kernel(const int* __restrict__ counts,
                                                    const int* __restrict__ blockoff,
                                                    int* __restrict__ indptr, int N, int NB) {
  int tid = threadIdx.x;
  int base = blockIdx.x * 1024 + tid * 4;
  int c0 = 0, c1 = 0, c2 = 0, c3 = 0;
  if (base + 3 < N) {
    int4 v = *(const int4*)&counts[base];
    c0 = v.x; c1 = v.y; c2 = v.z; c3 = v.w;
  } else {
    if (base + 0 < N) c0 = counts[base + 0];
    if (base + 1 < N) c1 = counts[base + 1];
    if (base + 2 < N) c2 = counts[base + 2];
    if (base + 3 < N) c3 = counts[base + 3];
  }
  int s = c0 + c1 + c2 + c3;
  __shared__ int sc[256];
  sc[tid] = s;
  __syncthreads();
  for (int off = 1; off < 256; off <<= 1) {
    int t = (tid >= off) ? sc[tid - off] : 0;
    __syncthreads();
    sc[tid] += t;
    __syncthreads();
  }
  int p = sc[tid] - s + blockoff[blockIdx.x];
  if (base + 0 < N) { indptr[base + 0] = p; p += c0; }
  if (base + 1 < N) { indptr[base + 1] = p; p += c1; }
  if (base + 2 < N) { indptr[base + 2] = p; p += c2; }
  if (base + 3 < N) { indptr[base + 3] = p; p += c3; }
  if (blockIdx.x == 0 && tid == 0) indptr[N] = blockoff[NB];
}

// fill (atomic-free via rank) fused with layer-1 edge weights.
__global__ __launch_bounds__(256) void fillw_kernel(const int* __restrict__ ei, int E, int N,
                                                    const int* __restrict__ indptr,
                                                    const int* __restrict__ rank,
                                                    int* __restrict__ srcs,
                                                    const float* __restrict__ asrc,
                                                    const float* __restrict__ adst,
                                                    float* __restrict__ w) {
  int e = blockIdx.x * 256 + threadIdx.x;
  if (e >= E + N) return;
  int src, dst;
  if (e < E) { src = ei[e]; dst = ei[(size_t)E + e]; }
  else       { src = e - E; dst = e - E; }
  int pos = indptr[dst] + rank[e];
  srcs[pos] = src;
  float4 as = *(const float4*)&asrc[src * 4];
  float4 ad = *(const float4*)&adst[dst * 4];
  float e0 = as.x + ad.x; e0 = (e0 > 0.f) ? e0 : 0.2f * e0;
  float e1 = as.y + ad.y; e1 = (e1 > 0.f) ? e1 : 0.2f * e1;
  float e2 = as.z + ad.z; e2 = (e2 > 0.f) ? e2 : 0.2f * e2;
  float e3 = as.w + ad.w; e3 = (e3 > 0.f) ? e3 : 0.2f * e3;
  *(float4*)&w[pos * 4] = make_float4(__expf(e0), __expf(e1), __expf(e2), __expf(e3));
}

// ---------------------------------------------------------------------------
// gemm1 fused: H1f8[M,256](fp8 e4m3) = x[M,256](f32) @ W1t^T, alpha1 epilogue.
// BM=128, BN=256, BK=32; 512 threads; LDT3=56; LDS 43KB -> 3 blocks/CU.
// ---------------------------------------------------------------------------

#define LDT2 72   // gemm2 pad
#define LDT3 56   // gemm1 pad (BK=32)

__global__ __launch_bounds__(512) void gemm1_fused(const float* __restrict__ A,
                                                   const unsigned short* __restrict__ Bt,
                                                   unsigned char* __restrict__ C,
                                                   const float* __restrict__ a_src,
                                                   const float* __restrict__ a_dst,
                                                   float* __restrict__ asrc,
                                                   float* __restrict__ adst, int M) {
  const int K = 256;
  __shared__ unsigned short As[128 * LDT3];
  __shared__ unsigned short Bs[256 * LDT3];
  int bm = blockIdx.x * 128;
  int tid = threadIdx.x;
  int wid = tid >> 6, lane = tid & 63;
  int wr = (wid >> 1) * 32, wc = (wid & 1) * 128;
  int l15 = lane & 15, lq = lane >> 4;

  f32x4 acc[2][8];
  #pragma unroll
  for (int i = 0; i < 2; ++i)
    #pragma unroll
    for (int f = 0; f < 8; ++f) acc[i][f] = (f32x4){0,0,0,0};

  for (int k0 = 0; k0 < K; k0 += 32) {
    {
      int r = tid >> 2, c = (tid & 3) * 8;
      int row = bm + r;
      float4 v0 = make_float4(0.f,0.f,0.f,0.f), v1 = v0;
      if (row < M) {
        v0 = *(const float4*)&A[(size_t)row * K + k0 + c];
        v1 = *(const float4*)&A[(size_t)row * K + k0 + c + 4];
      }
      ushort8 o;
      o[0]=f2bf(v0.x); o[1]=f2bf(v0.y); o[2]=f2bf(v0.z); o[3]=f2bf(v0.w);
      o[4]=f2bf(v1.x); o[5]=f2bf(v1.y); o[6]=f2bf(v1.z); o[7]=f2bf(v1.w);
      *(ushort8*)&As[r * LDT3 + c] = o;
    }
    {
      int r = tid >> 1, seg = (tid & 1) * 16;
      ushort8 v0 = *(const ushort8*)&Bt[(size_t)r * K + k0 + seg];
      ushort8 v1 = *(const ushort8*)&Bt[(size_t)r * K + k0 + seg + 8];
      *(ushort8*)&Bs[r * LDT3 + seg]     = v0;
      *(ushort8*)&Bs[r * LDT3 + seg + 8] = v1;
    }
    __syncthreads();

    short8 a0 = *(const short8*)&As[(wr + l15) * LDT3 + lq * 8];
    short8 a1 = *(const short8*)&As[(wr + 16 + l15) * LDT3 + lq * 8];
    #pragma unroll
    for (int f = 0; f < 8; ++f) {
      short8 b = *(const short8*)&Bs[(wc + f * 16 + l15) * LDT3 + lq * 8];
      acc[0][f] = __builtin_amdgcn_mfma_f32_16x16x32_bf16(a0, b, acc[0][f], 0, 0, 0);
      acc[1][f] = __builtin_amdgcn_mfma_f32_16x16x32_bf16(a1, b, acc[1][f], 0, 0, 0);
    }
    __syncthreads();
  }

  #pragma unroll
  for (int r = 0; r < 4; ++r) {
    int row0 = bm + wr + lq * 4 + r;
    int row1 = row0 + 16;
    #pragma unroll
    for (int f = 0; f < 8; ++f) {
      int col = wc + f * 16 + l15;
      if (row0 < M) C[(size_t)row0 * 256 + col] = f2fp8(acc[0][f][r]);
      if (row1 < M) C[(size_t)row1 * 256 + col] = f2fp8(acc[1][f][r]);
    }
  }

  float ps[2][4][2], pd[2][4][2];
  #pragma unroll
  for (int i = 0; i < 2; ++i)
    #pragma unroll
    for (int r = 0; r < 4; ++r) { ps[i][r][0]=0.f; ps[i][r][1]=0.f; pd[i][r][0]=0.f; pd[i][r][1]=0.f; }
  #pragma unroll
  for (int f = 0; f < 8; ++f) {
    int col = wc + f * 16 + l15;
    float av = a_src[col], dv = a_dst[col];
    int hh = f >> 2;
    #pragma unroll
    for (int i = 0; i < 2; ++i)
      #pragma unroll
      for (int r = 0; r < 4; ++r) {
        ps[i][r][hh] += acc[i][f][r] * av;
        pd[i][r][hh] += acc[i][f][r] * dv;
      }
  }
  #pragma unroll
  for (int off = 1; off < 16; off <<= 1) {
    #pragma unroll
    for (int i = 0; i < 2; ++i)
      #pragma unroll
      for (int r = 0; r < 4; ++r) {
        ps[i][r][0] += __shfl_xor(ps[i][r][0], off);
        ps[i][r][1] += __shfl_xor(ps[i][r][1], off);
        pd[i][r][0] += __shfl_xor(pd[i][r][0], off);
        pd[i][r][1] += __shfl_xor(pd[i][r][1], off);
      }
  }
  if (l15 == 0) {
    int hb = wc >> 6;
    #pragma unroll
    for (int i = 0; i < 2; ++i)
      #pragma unroll
      for (int r = 0; r < 4; ++r) {
        int row = bm + wr + lq * 4 + r + i * 16;
        if (row < M) {
          asrc[row * 4 + hb]     = ps[i][r][0];
          asrc[row * 4 + hb + 1] = ps[i][r][1];
          adst[row * 4 + hb]     = pd[i][r][0];
          adst[row * 4 + hb + 1] = pd[i][r][1];
        }
      }
  }
}

// ---------------------------------------------------------------------------
// gemm2 fused: H2b[M,64](bf16) = X2b[M,256](bf16) @ W2t^T, alpha2 in epilogue.
// ---------------------------------------------------------------------------

__global__ __launch_bounds__(256) void gemm2_fused(const unsigned short* __restrict__ A,
                                                   const unsigned short* __restrict__ Bt,
                                                   unsigned short* __restrict__ C,
                                                   const float* __restrict__ a_src,
                                                   const float* __restrict__ a_dst,
                                                   float* __restrict__ asrc,
                                                   float* __restrict__ adst, int M) {
  const int K = 256;
  __shared__ unsigned short As[64 * LDT2];
  __shared__ unsigned short Bs[64 * LDT2];
  __shared__ float sred[64], dred[64];
  int bm = blockIdx.x * 64;
  int tid = threadIdx.x;
  int wid = tid >> 6, lane = tid & 63;
  int wr = (wid >> 1) * 32, wc = (wid & 1) * 32;
  int l15 = lane & 15, lq = lane >> 4;

  f32x4 acc[2][2];
  #pragma unroll
  for (int i = 0; i < 2; ++i) { acc[i][0] = (f32x4){0,0,0,0}; acc[i][1] = (f32x4){0,0,0,0}; }

  for (int k0 = 0; k0 < K; k0 += 64) {
    {
      int r = tid >> 2, seg = (tid & 3) * 16;
      int row = bm + r;
      ushort8 v0 = {0,0,0,0,0,0,0,0}, v1 = {0,0,0,0,0,0,0,0};
      if (row < M) {
        v0 = *(const ushort8*)&A[(size_t)row * K + k0 + seg];
        v1 = *(const ushort8*)&A[(size_t)row * K + k0 + seg + 8];
      }
      *(ushort8*)&As[r * LDT2 + seg]     = v0;
      *(ushort8*)&As[r * LDT2 + seg + 8] = v1;
    }
    {
      int r = tid >> 2, seg = (tid & 3) * 16;
      ushort8 v0 = *(const ushort8*)&Bt[(size_t)r * K + k0 + seg];
      ushort8 v1 = *(const ushort8*)&Bt[(size_t)r * K + k0 + seg + 8];
      *(ushort8*)&Bs[r * LDT2 + seg]     = v0;
      *(ushort8*)&Bs[r * LDT2 + seg + 8] = v1;
    }
    __syncthreads();

    #pragma unroll
    for (int ks = 0; ks < 2; ++ks) {
      short8 a0 = *(const short8*)&As[(wr + l15) * LDT2 + ks * 32 + lq * 8];
      short8 a1 = *(const short8*)&As[(wr + 16 + l15) * LDT2 + ks * 32 + lq * 8];
      #pragma unroll
      for (int f = 0; f < 2; ++f) {
        short8 b = *(const short8*)&Bs[(wc + f * 16 + l15) * LDT2 + ks * 32 + lq * 8];
        acc[0][f] = __builtin_amdgcn_mfma_f32_16x16x32_bf16(a0, b, acc[0][f], 0, 0, 0);
        acc[1][f] = __builtin_amdgcn_mfma_f32_16x16x32_bf16(a1, b, acc[1][f], 0, 0, 0);
      }
    }
    __syncthreads();
  }

  #pragma unroll
  for (int r = 0; r < 4; ++r) {
    int row0 = bm + wr + lq * 4 + r;
    int row1 = row0 + 16;
    #pragma unroll
    for (int f = 0; f < 2; ++f) {
      int col = wc + f * 16 + l15;
      if (row0 < M) C[(size_t)row0 * 64 + col] = f2bf(acc[0][f][r]);
      if (row1 < M) C[(size_t)row1 * 64 + col] = f2bf(acc[1][f][r]);
    }
  }

  float ps[2][4], pd[2][4];
  #pragma unroll
  for (int i = 0; i < 2; ++i)
    #pragma unroll
    for (int r = 0; r < 4; ++r) { ps[i][r] = 0.f; pd[i][r] = 0.f; }
  #pragma unroll
  for (int f = 0; f < 2; ++f) {
    int col = wc + f * 16 + l15;
    float av = a_src[col], dv = a_dst[col];
    #pragma unroll
    for (int i = 0; i < 2; ++i)
      #pragma unroll
      for (int r = 0; r < 4; ++r) {
        ps[i][r] += acc[i][f][r] * av;
        pd[i][r] += acc[i][f][r] * dv;
      }
  }
  #pragma unroll
  for (int off = 1; off < 16; off <<= 1) {
    #pragma unroll
    for (int i = 0; i < 2; ++i)
      #pragma unroll
      for (int r = 0; r < 4; ++r) {
        ps[i][r] += __shfl_xor(ps[i][r], off);
        pd[i][r] += __shfl_xor(pd[i][r], off);
      }
  }
  if ((wid & 1) == 0 && l15 == 0) {
    #pragma unroll
    for (int i = 0; i < 2; ++i)
      #pragma unroll
      for (int r = 0; r < 4; ++r) {
        int rl = wr + lq * 4 + r + i * 16;
        sred[rl] = ps[i][r];
        dred[rl] = pd[i][r];
      }
  }
  __syncthreads();
  if ((wid & 1) == 1 && l15 == 0) {
    #pragma unroll
    for (int i = 0; i < 2; ++i)
      #pragma unroll
      for (int r = 0; r < 4; ++r) {
        int rl = wr + lq * 4 + r + i * 16;
        int row = bm + rl;
        if (row < M) {
          asrc[row] = sred[rl] + ps[i][r];
          adst[row] = dred[rl] + pd[i][r];
        }
      }
  }
}

// ---------------------------------------------------------------------------
// GAT agg layer 1 (fp8 H1): split-wave (2 edges), 8B/lane, 4x unroll,
// packed f32x2 accumulators (v_pk_fma_f32 path). 256-thread blocks.
// ---------------------------------------------------------------------------

__global__ __launch_bounds__(256) void gat1_agg(const unsigned char* __restrict__ H1f8,
                                                const float* __restrict__ w,
                                                const int* __restrict__ indptr,
                                                const int* __restrict__ srcs,
                                                const float* __restrict__ b1,
                                                const float* __restrict__ g1,
                                                const float* __restrict__ be1,
                                                const float* __restrict__ mu1,
                                                const float* __restrict__ var1,
                                                unsigned short* __restrict__ X2b, int N) {
  int n = blockIdx.x * 4 + (threadIdx.x >> 6);
  if (n >= N) return;
  int lane = threadIdx.x & 63;
  int half = lane >> 5;
  int j = lane & 31;
  int h = j >> 3;
  int start = indptr[n], end = indptr[n + 1];

  f32x2 acc2[4];
  #pragma unroll
  for (int i = 0; i < 4; ++i) acc2[i] = (f32x2){0.f, 0.f};
  float wsum = 0.f;
  int k = start + half;
  for (; k + 6 < end; k += 8) {
    int s0 = srcs[k], s1 = srcs[k + 2], s2 = srcs[k + 4], s3 = srcs[k + 6];
    float w0 = w[k * 4 + h], w1v = w[(k + 2) * 4 + h];
    float w2v = w[(k + 4) * 4 + h], w3v = w[(k + 6) * 4 + h];
    uint2 u0 = *(const uint2*)&H1f8[(size_t)s0 * C1 + j * 8];
    uint2 u1 = *(const uint2*)&H1f8[(size_t)s1 * C1 + j * 8];
    uint2 u2 = *(const uint2*)&H1f8[(size_t)s2 * C1 + j * 8];
    uint2 u3 = *(const uint2*)&H1f8[(size_t)s3 * C1 + j * 8];
    wsum += (w0 + w1v) + (w2v + w3v);
    {
      f32x2 wv = (f32x2){w0, w0};
      acc2[0] += wv * __builtin_amdgcn_cvt_pk_f32_fp8(u0.x, false);
      acc2[1] += wv * __builtin_amdgcn_cvt_pk_f32_fp8(u0.x, true);
      acc2[2] += wv * __builtin_amdgcn_cvt_pk_f32_fp8(u0.y, false);
      acc2[3] += wv * __builtin_amdgcn_cvt_pk_f32_fp8(u0.y, true);
    }
    {
      f32x2 wv = (f32x2){w1v, w1v};
      acc2[0] += wv * __builtin_amdgcn_cvt_pk_f32_fp8(u1.x, false);
      acc2[1] += wv * __builtin_amdgcn_cvt_pk_f32_fp8(u1.x, true);
      acc2[2] += wv * __builtin_amdgcn_cvt_pk_f32_fp8(u1.y, false);
      acc2[3] += wv * __builtin_amdgcn_cvt_pk_f32_fp8(u1.y, true);
    }
    {
      f32x2 wv = (f32x2){w2v, w2v};
      acc2[0] += wv * __builtin_amdgcn_cvt_pk_f32_fp8(u2.x, false);
      acc2[1] += wv * __builtin_amdgcn_cvt_pk_f32_fp8(u2.x, true);
      acc2[2] += wv * __builtin_amdgcn_cvt_pk_f32_fp8(u2.y, false);
      acc2[3] += wv * __builtin_amdgcn_cvt_pk_f32_fp8(u2.y, true);
    }
    {
      f32x2 wv = (f32x2){w3v, w3v};
      acc2[0] += wv * __builtin_amdgcn_cvt_pk_f32_fp8(u3.x, false);
      acc2[1] += wv * __builtin_amdgcn_cvt_pk_f32_fp8(u3.x, true);
      acc2[2] += wv * __builtin_amdgcn_cvt_pk_f32_fp8(u3.y, false);
      acc2[3] += wv * __builtin_amdgcn_cvt_pk_f32_fp8(u3.y, true);
    }
  }
  for (; k < end; k += 2) {
    int s0 = srcs[k];
    float w0 = w[k * 4 + h];
    uint2 u0 = *(const uint2*)&H1f8[(size_t)s0 * C1 + j * 8];
    wsum += w0;
    f32x2 wv = (f32x2){w0, w0};
    acc2[0] += wv * __builtin_amdgcn_cvt_pk_f32_fp8(u0.x, false);
    acc2[1] += wv * __builtin_amdgcn_cvt_pk_f32_fp8(u0.x, true);
    acc2[2] += wv * __builtin_amdgcn_cvt_pk_f32_fp8(u0.y, false);
    acc2[3] += wv * __builtin_amdgcn_cvt_pk_f32_fp8(u0.y, true);
  }
  float acc[8];
  #pragma unroll
  for (int i = 0; i < 4; ++i) { acc[2*i] = acc2[i][0]; acc[2*i+1] = acc2[i][1]; }
  #pragma unroll
  for (int i = 0; i < 8; ++i) acc[i] += __shfl_xor(acc[i], 32);
  wsum += __shfl_xor(wsum, 32);

  if (half == 0) {
    float inv = 1.f / (wsum + 1e-16f);
    int f = j * 8;
    ushort8 o;
    #pragma unroll
    for (int i = 0; i < 8; ++i) {
      float val = (acc[i] * inv + b1[f + i] - mu1[f + i]) *
                  (g1[f + i] * rsqrtf(var1[f + i] + 1e-5f)) + be1[f + i];
      val = (val > 0.f) ? val : (__expf(val) - 1.f);
      o[i] = f2bf(val);
    }
    *(ushort8*)&X2b[(size_t)n * C1 + f] = o;
  }
}

// ---------------------------------------------------------------------------
// GAT agg layer 2 (fused edge weights, 8-slot geometry): wave per node,
// 8 edge slots, 16B/lane, 2x unroll; w computed inline from asrc2 (L2-hot).
// 256-thread blocks.
// ---------------------------------------------------------------------------

__global__ __launch_bounds__(256) void gat2_agg(const unsigned short* __restrict__ H2b,
                                                const float* __restrict__ asrc,
                                                const float* __restrict__ adst,
                                                const int* __restrict__ indptr,
                                                const int* __restrict__ srcs,
                                                const float* __restrict__ b2,
                                                const float* __restrict__ g2,
                                                const float* __restrict__ be2,
                                                const float* __restrict__ mu2,
                                                const float* __restrict__ var2,
                                                float* __restrict__ out, int N) {
  int n = blockIdx.x * 4 + (threadIdx.x >> 6);
  if (n >= N) return;
  int lane = threadIdx.x & 63;
  int q = lane >> 3;
  int j = lane & 7;
  int start = indptr[n], end = indptr[n + 1];
  float ad = adst[n];

  float acc[8];
  #pragma unroll
  for (int i = 0; i < 8; ++i) acc[i] = 0.f;
  float wsum = 0.f;

  int k = start + q;
  for (; k + 8 < end; k += 16) {
    int s0 = srcs[k], s1 = srcs[k + 8];
    float e0 = asrc[s0] + ad; e0 = (e0 > 0.f) ? e0 : 0.2f * e0;
    float e1 = asrc[s1] + ad; e1 = (e1 > 0.f) ? e1 : 0.2f * e1;
    float w0 = __expf(e0), w1v = __expf(e1);
    ushort8 r0 = *(const ushort8*)&H2b[(size_t)s0 * HID + j * 8];
    ushort8 r1 = *(const ushort8*)&H2b[(size_t)s1 * HID + j * 8];
    wsum += w0 + w1v;
    #pragma unroll
    for (int i = 0; i < 8; ++i)
      acc[i] += w0 * bf2f(r0[i]) + w1v * bf2f(r1[i]);
  }
  if (k < end) {
    int s0 = srcs[k];
    float e0 = asrc[s0] + ad; e0 = (e0 > 0.f) ? e0 : 0.2f * e0;
    float w0 = __expf(e0);
    ushort8 r0 = *(const ushort8*)&H2b[(size_t)s0 * HID + j * 8];
    wsum += w0;
    #pragma unroll
    for (int i = 0; i < 8; ++i) acc[i] += w0 * bf2f(r0[i]);
  }
  #pragma unroll
  for (int i = 0; i < 8; ++i) {
    acc[i] += __shfl_xor(acc[i], 8);
    acc[i] += __shfl_xor(acc[i], 16);
    acc[i] += __shfl_xor(acc[i], 32);
  }
  wsum += __shfl_xor(wsum, 8);
  wsum += __shfl_xor(wsum, 16);
  wsum += __shfl_xor(wsum, 32);

  if (q == 0) {
    float inv = 1.f / (wsum + 1e-16f);
    int f = j * 8;
    float o[8];
    #pragma unroll
    for (int i = 0; i < 8; ++i) {
      float val = (acc[i] * inv + b2[f + i] - mu2[f + i]) *
                  (g2[f + i] * rsqrtf(var2[f + i] + 1e-5f)) + be2[f + i];
      o[i] = (val > 0.f) ? val : (__expf(val) - 1.f);
    }
    *(float4*)&out[(size_t)n * HID + f]     = make_float4(o[0], o[1], o[2], o[3]);
    *(float4*)&out[(size_t)n * HID + f + 4] = make_float4(o[4], o[5], o[6], o[7]);
  }
}

// ---------------------------------------------------------------------------

extern "C" void kernel_launch(void* const* d_in, const int* in_sizes, int n_in,
                              void* d_out, int out_size, void* d_ws, size_t ws_size,
                              hipStream_t stream) {
  const float* x      = (const float*)d_in[0];
  const int*   ei     = (const int*)d_in[1];
  const float* W1     = (const float*)d_in[2];
  const float* a_src1 = (const float*)d_in[3];
  const float* a_dst1 = (const float*)d_in[4];
  const float* b1     = (const float*)d_in[5];
  const float* g1     = (const float*)d_in[6];
  const float* be1    = (const float*)d_in[7];
  const float* mu1    = (const float*)d_in[8];
  const float* var1   = (const float*)d_in[9];
  const float* W2     = (const float*)d_in[10];
  const float* a_src2 = (const float*)d_in[11];
  const float* a_dst2 = (const float*)d_in[12];
  const float* b2     = (const float*)d_in[13];
  const float* g2     = (const float*)d_in[14];
  const float* be2    = (const float*)d_in[15];
  const float* mu2    = (const float*)d_in[16];
  const float* var2   = (const float*)d_in[17];
  float* out = (float*)d_out;

  int N = in_sizes[0] / IN_DIM;
  int E = in_sizes[1] / 2;
  int Etot = E + N;
  int NB = (N + 1023) / 1024;

  unsigned short* H1region = (unsigned short*)d_ws;
  unsigned char*  H1f8 = (unsigned char*)H1region;
  unsigned short* X2b = H1region + (size_t)N * C1;
  unsigned short* W1t = X2b + (size_t)N * C1;
  unsigned short* W2t = W1t + 256 * 256;
  float* w1    = (float*)(W2t + 64 * 256);
  float* asrc1 = w1 + (size_t)4 * Etot;
  float* adst1 = asrc1 + (size_t)N * HEADS;
  float* asrc2 = adst1 + (size_t)N * HEADS;
  float* adst2 = asrc2 + N;
  int* counts    = (int*)(adst2 + N);
  int* indptr    = counts + N;
  int* blocksums = indptr + (N + 1);
  int* blockoff  = blocksums + NB;
  int* done      = blockoff + (NB + 1);
  int* rank      = done + 1;
  int* srcs      = rank + Etot;
  unsigned short* H2b = H1region;   // H1 fp8 dead after gat1_agg

  // --- prep + CSR build (rank trick) ---
  prep_kernel<<<(256 * 256 + 64 * 256 + N + 255) / 256, 256, 0, stream>>>(
      W1, W1t, W2, W2t, counts, done, N);
  hist_kernel<<<(Etot + 255) / 256, 256, 0, stream>>>(ei, E, N, counts, rank);
  scan12_kernel<<<NB, 256, 0, stream>>>(counts, blocksums, blockoff, done, N, NB);
  scan3_kernel<<<NB, 256, 0, stream>>>(counts, blockoff, indptr, N, NB);

  // --- Layer 1 ---
  gemm1_fused<<<(N + 127) / 128, 512, 0, stream>>>(x, W1t, H1f8, a_src1, a_dst1,
                                                   asrc1, adst1, N);
  fillw_kernel<<<(Etot + 255) / 256, 256, 0, stream>>>(ei, E, N, indptr, rank, srcs,
                                                       asrc1, adst1, w1);
  gat1_agg<<<(N + 3) / 4, 256, 0, stream>>>(H1f8, w1, indptr, srcs,
                                            b1, g1, be1, mu1, var1, X2b, N);

  // --- Layer 2 ---
  gemm2_fused<<<(N + 63) / 64, 256, 0, stream>>>(X2b, W2t, H2b, a_src2, a_dst2,
                                                 asrc2, adst2, N);
  gat2_agg<<<(N + 3) / 4, 256, 0, stream>>>(H2b, asrc2, adst2, indptr, srcs,
                                            b2, g2, be2, mu2, var2, out, N);
}